// Round 5
// baseline (147.117 us; speedup 1.0000x reference)
//
#include <hip/hip_runtime.h>

// Rowwise cosine similarity, two-phase.
// a, b: [16, 4096, 256] f32 -> 65536 rows of 256 floats (64 float4 per row).
//
// Phase 1 (pure streaming, no cross-lane ops, no load->reduce->store chain):
//   thread g -> row = g>>4, sub = g&15. Loads float4s {sub, sub+16, sub+32,
//   sub+48} of its row for a and b (8 independent dwordx4 loads, wave access
//   = 4 x 256 B segments per instruction = same 16 cache lines as a fully
//   contiguous 1 KB load). Computes partial sa/sb/sab over its 16 elements
//   and stores 3 floats to d_ws (SoA, 64-dword-contiguous per wave,
//   fire-and-forget). 12.6 MB partials total.
// Phase 2 (tiny): 16-lane group per row reads the 16 partials per component
//   (coalesced), 4-level butterfly, lane 0 writes out[row]. ~13 MB, L2-hot.

#define EPS 1e-12f

__global__ __launch_bounds__(256) void cosine_phase1(
    const float4* __restrict__ a4,
    const float4* __restrict__ b4,
    float* __restrict__ ws_sa,
    float* __restrict__ ws_sb,
    float* __restrict__ ws_sab,
    int n_part)                      // n_rows * 16
{
    const int g = blockIdx.x * 256 + threadIdx.x;
    if (g >= n_part) return;
    const int row = g >> 4;
    const int sub = g & 15;

    const float4* __restrict__ ar = a4 + (size_t)row * 64 + sub;
    const float4* __restrict__ br = b4 + (size_t)row * 64 + sub;

    // 8 independent loads, all issued before any use.
    float4 av0 = ar[0],  av1 = ar[16], av2 = ar[32], av3 = ar[48];
    float4 bv0 = br[0],  bv1 = br[16], bv2 = br[32], bv3 = br[48];

    float sa = 0.f, sb = 0.f, sab = 0.f;
    #define ACC(av, bv)                                                       \
        sa  = fmaf(av.x, av.x, fmaf(av.y, av.y, fmaf(av.z, av.z, fmaf(av.w, av.w, sa))));   \
        sb  = fmaf(bv.x, bv.x, fmaf(bv.y, bv.y, fmaf(bv.z, bv.z, fmaf(bv.w, bv.w, sb))));   \
        sab = fmaf(av.x, bv.x, fmaf(av.y, bv.y, fmaf(av.z, bv.z, fmaf(av.w, bv.w, sab))));
    ACC(av0, bv0)
    ACC(av1, bv1)
    ACC(av2, bv2)
    ACC(av3, bv3)
    #undef ACC

    ws_sa[g]  = sa;     // coalesced: wave writes 64 contiguous dwords per array
    ws_sb[g]  = sb;
    ws_sab[g] = sab;
}

__global__ __launch_bounds__(256) void cosine_phase2(
    const float* __restrict__ ws_sa,
    const float* __restrict__ ws_sb,
    const float* __restrict__ ws_sab,
    float* __restrict__ out,
    int n_part)                      // n_rows * 16
{
    const int g = blockIdx.x * 256 + threadIdx.x;
    if (g >= n_part) return;
    const int sub = g & 15;
    const int row = g >> 4;

    float sa  = ws_sa[g];
    float sb  = ws_sb[g];
    float sab = ws_sab[g];

    #pragma unroll
    for (int off = 8; off > 0; off >>= 1) {
        sa  += __shfl_xor(sa,  off, 16);
        sb  += __shfl_xor(sb,  off, 16);
        sab += __shfl_xor(sab, off, 16);
    }

    if (sub == 0)
        out[row] = sab * rsqrtf(fmaxf(sa, EPS)) * rsqrtf(fmaxf(sb, EPS));
}

extern "C" void kernel_launch(void* const* d_in, const int* in_sizes, int n_in,
                              void* d_out, int out_size, void* d_ws, size_t ws_size,
                              hipStream_t stream)
{
    const float4* a4 = (const float4*)d_in[0];
    const float4* b4 = (const float4*)d_in[1];
    float* out = (float*)d_out;

    const int n_rows = out_size;          // 16 * 4096 = 65536
    const int n_part = n_rows * 16;       // 1,048,576 partial slots

    float* ws_sa  = (float*)d_ws;
    float* ws_sb  = ws_sa + n_part;
    float* ws_sab = ws_sb + n_part;       // 3 * 4 MB = 12.6 MB of d_ws

    const int grid = (n_part + 255) / 256;   // 4096 blocks
    cosine_phase1<<<grid, 256, 0, stream>>>(a4, b4, ws_sa, ws_sb, ws_sab, n_part);
    cosine_phase2<<<grid, 256, 0, stream>>>(ws_sa, ws_sb, ws_sab, out, n_part);
}

// Round 6
// 137.356 us; speedup vs baseline: 1.0711x; 1.0711x over previous
//
#include <hip/hip_runtime.h>

// Rowwise cosine similarity: out[r] = dot(a_r,b_r) * rsqrt(max(|a_r|^2,eps)) * rsqrt(max(|b_r|^2,eps))
// a, b: [16, 4096, 256] f32 -> 65536 rows of 256 floats.
//
// Wave-per-row (best measured structure, R1: ~40 us):
//   lane i loads float4 i of the row for a and b -> 64 x 16 B = 1 KB
//   contiguous per instruction, perfectly coalesced; 6-step shfl_xor
//   butterfly; lane 0 stores.
//
// Measured ceiling evidence (R1/R2/R4/R5): four different structures all
// deliver 3.0-3.4 TB/s pure-read regardless of MLP/pipelining/persistence
// -> hardware read-path cap (~outstanding-line buffer x latency, or per-XCD
// read port). This kernel sits at that ceiling; reads are single-pass.

#define D 256
#define EPS 1e-12f

__global__ __launch_bounds__(256) void cosine_rows_kernel(
    const float* __restrict__ a,
    const float* __restrict__ b,
    float* __restrict__ out,
    int n_rows)
{
    const int lane = threadIdx.x & 63;
    const int wave = threadIdx.x >> 6;            // 4 waves per block
    const int row  = blockIdx.x * 4 + wave;
    if (row >= n_rows) return;

    const float4* a4 = reinterpret_cast<const float4*>(a + (size_t)row * D);
    const float4* b4 = reinterpret_cast<const float4*>(b + (size_t)row * D);

    float4 av = a4[lane];
    float4 bv = b4[lane];

    float sa  = av.x * av.x + av.y * av.y + av.z * av.z + av.w * av.w;
    float sb  = bv.x * bv.x + bv.y * bv.y + bv.z * bv.z + bv.w * bv.w;
    float sab = av.x * bv.x + av.y * bv.y + av.z * bv.z + av.w * bv.w;

    // 64-lane butterfly reduction
    #pragma unroll
    for (int off = 32; off > 0; off >>= 1) {
        sa  += __shfl_xor(sa,  off, 64);
        sb  += __shfl_xor(sb,  off, 64);
        sab += __shfl_xor(sab, off, 64);
    }

    if (lane == 0) {
        out[row] = sab * rsqrtf(fmaxf(sa, EPS)) * rsqrtf(fmaxf(sb, EPS));
    }
}

extern "C" void kernel_launch(void* const* d_in, const int* in_sizes, int n_in,
                              void* d_out, int out_size, void* d_ws, size_t ws_size,
                              hipStream_t stream)
{
    const float* a = (const float*)d_in[0];
    const float* b = (const float*)d_in[1];
    float* out = (float*)d_out;

    const int n_rows = out_size;            // 16 * 4096 = 65536
    const int rows_per_block = 4;           // 256 threads = 4 waves
    const int grid = (n_rows + rows_per_block - 1) / rows_per_block;

    cosine_rows_kernel<<<grid, 256, 0, stream>>>(a, b, out, n_rows);
}